// Round 1
// baseline (478.263 us; speedup 1.0000x reference)
//
#include <hip/hip_runtime.h>
#include <cstdint>
#include <cstddef>

typedef unsigned short u16;
typedef __attribute__((ext_vector_type(4))) float f32x4;
typedef __attribute__((ext_vector_type(8))) short s16x8;
typedef __attribute__((ext_vector_type(4))) short s16x4;

#define D_M   1024
#define KDIM  1024
#define BB    4
#define LL    8192
#define MTOT  (BB*LL)
#define CHK   128
#define NCH   (LL/CHK)
#define LN_EPS 1e-5f

static __device__ __forceinline__ float bf2f(u16 u){
  return __uint_as_float(((unsigned)u)<<16);
}
static __device__ __forceinline__ u16 f2bf(float f){
  unsigned u = __float_as_uint(f);
  u += 0x7fffu + ((u>>16)&1u);
  return (u16)(u>>16);
}

// fp32 -> bf16 vectorized convert
__global__ void conv_f2b_k(const float* __restrict__ src, u16* __restrict__ dst, int n4){
  int i = blockIdx.x*blockDim.x + threadIdx.x;
  int stride = gridDim.x*blockDim.x;
  for (; i < n4; i += stride){
    f32x4 f = ((const f32x4*)src)[i];
    s16x4 o;
    o[0]=(short)f2bf(f[0]); o[1]=(short)f2bf(f[1]);
    o[2]=(short)f2bf(f[2]); o[3]=(short)f2bf(f[3]);
    ((s16x4*)dst)[i] = o;
  }
}

// C[M,N] = A[M,K] @ W[N,K]^T, bf16 inputs, fp32 accumulate.
// 128x128 tile, BK=64, 4 waves (2x2), each wave 64x64 via 4x4 frags of 16x16x32.
// global_load_lds(16B) with pre-swizzled global source; ds_read uses matching XOR swizzle:
//   LDS[row][slot] holds global k-chunk kc = slot ^ (row&7)  (16B chunks, row=128B)
template<int F32OUT>
__global__ __launch_bounds__(256,2) void gemm_bt(
    const u16* __restrict__ A,
    const u16* __restrict__ W0, const u16* __restrict__ W1, const u16* __restrict__ W2,
    void* __restrict__ O0, void* __restrict__ O1, void* __restrict__ O2)
{
  __shared__ __align__(16) u16 As[128*64];
  __shared__ __align__(16) u16 Bs[128*64];
  const int mode = blockIdx.z;
  const u16* W = (mode==0)? W0 : ((mode==1)? W1 : W2);
  void* Ov     = (mode==0)? O0 : ((mode==1)? O1 : O2);

  const int tid  = threadIdx.x;
  const int wave = tid>>6, lane = tid&63;
  const int bm = blockIdx.x*128, bn = blockIdx.y*128;

  // staging: chunk id c = it*256 + wave*64 + lane maps to LDS byte c*16 (linear dest),
  // global source row = c>>3, k-chunk = (c&7) ^ (row&7)
  size_t ga[4], gb[4];
  int lbase[4];
  #pragma unroll
  for (int it=0; it<4; ++it){
    int c    = it*256 + wave*64 + lane;
    int mch  = c>>3;
    int k16  = (c&7) ^ (mch&7);
    ga[it] = (size_t)(bm + mch)*KDIM + (size_t)k16*8;
    gb[it] = (size_t)(bn + mch)*KDIM + (size_t)k16*8;
    lbase[it] = (it*256 + wave*64)*8;  // u16 elements (uniform per wave)
  }

  const int lr = lane&15, lk = lane>>4;
  const int wm = (wave>>1)*64, wn = (wave&1)*64;
  int a_off[4][2], b_off[4][2];
  #pragma unroll
  for (int mi=0; mi<4; ++mi){
    #pragma unroll
    for (int kp=0; kp<2; ++kp){
      int slot = ((kp*4 + lk) ^ (lr&7));
      a_off[mi][kp] = (wm + mi*16 + lr)*128 + slot*16;  // bytes
      b_off[mi][kp] = (wn + mi*16 + lr)*128 + slot*16;
    }
  }

  const f32x4 fzero = {0.f,0.f,0.f,0.f};
  f32x4 acc[4][4];
  #pragma unroll
  for (int i=0;i<4;i++)
    #pragma unroll
    for (int j=0;j<4;j++)
      acc[i][j] = fzero;

  const char* Asc = (const char*)As;
  const char* Bsc = (const char*)Bs;

  for (int kt=0; kt<KDIM/64; ++kt){
    if (kt) __syncthreads();
    #pragma unroll
    for (int it=0; it<4; ++it){
      __builtin_amdgcn_global_load_lds(
        (const __attribute__((address_space(1))) void*)(A + ga[it] + (size_t)kt*64),
        (__attribute__((address_space(3))) void*)(As + lbase[it]), 16, 0, 0);
      __builtin_amdgcn_global_load_lds(
        (const __attribute__((address_space(1))) void*)(W + gb[it] + (size_t)kt*64),
        (__attribute__((address_space(3))) void*)(Bs + lbase[it]), 16, 0, 0);
    }
    __syncthreads();
    #pragma unroll
    for (int kp=0; kp<2; ++kp){
      s16x8 af[4], bfr[4];
      #pragma unroll
      for (int mi=0; mi<4; ++mi) af[mi]  = *(const s16x8*)(Asc + a_off[mi][kp]);
      #pragma unroll
      for (int ni=0; ni<4; ++ni) bfr[ni] = *(const s16x8*)(Bsc + b_off[ni][kp]);
      #pragma unroll
      for (int mi=0; mi<4; ++mi)
        #pragma unroll
        for (int ni=0; ni<4; ++ni)
          acc[mi][ni] = __builtin_amdgcn_mfma_f32_16x16x32_bf16(af[mi], bfr[ni], acc[mi][ni], 0,0,0);
    }
  }

  // C/D layout: col = lane&15, row = (lane>>4)*4 + reg  [m89/m91 verified]
  const int r0 = bm + wm + (lane>>4)*4;
  const int c0 = bn + wn + (lane&15);
  if (F32OUT){
    float* O = (float*)Ov;
    #pragma unroll
    for (int mi=0; mi<4; ++mi)
      #pragma unroll
      for (int ni=0; ni<4; ++ni)
        #pragma unroll
        for (int r=0;r<4;r++)
          O[(size_t)(r0 + mi*16 + r)*D_M + (c0 + ni*16)] = acc[mi][ni][r];
  } else {
    u16* O = (u16*)Ov;
    const bool do_silu = (mode==2);
    #pragma unroll
    for (int mi=0; mi<4; ++mi)
      #pragma unroll
      for (int ni=0; ni<4; ++ni)
        #pragma unroll
        for (int r=0;r<4;r++){
          float vv = acc[mi][ni][r];
          if (do_silu) vv = vv / (1.f + __expf(-vv));
          O[(size_t)(r0 + mi*16 + r)*D_M + (c0 + ni*16)] = f2bf(vv);
        }
  }
}

// pass 1: per-chunk local inclusive scan, in place over v; chunk-end -> E (fp32)
__global__ __launch_bounds__(256) void scan1_k(u16* __restrict__ v, float* __restrict__ E,
                                               const float* __restrict__ decay){
  const int c = blockIdx.x, b = blockIdx.y;
  const int d0 = threadIdx.x*4;
  const float lam = decay[d0>>6];
  float s0=0.f,s1=0.f,s2=0.f,s3=0.f;
  u16* p = v + ((size_t)b*LL + (size_t)c*CHK)*D_M + d0;
  for (int i=0;i<CHK;i++){
    s16x4 x = *(const s16x4*)p;
    s0 = fmaf(s0, lam, bf2f((u16)x[0]));
    s1 = fmaf(s1, lam, bf2f((u16)x[1]));
    s2 = fmaf(s2, lam, bf2f((u16)x[2]));
    s3 = fmaf(s3, lam, bf2f((u16)x[3]));
    s16x4 o;
    o[0]=(short)f2bf(s0); o[1]=(short)f2bf(s1);
    o[2]=(short)f2bf(s2); o[3]=(short)f2bf(s3);
    *(s16x4*)p = o;
    p += D_M;
  }
  f32x4 e = {s0,s1,s2,s3};
  *(f32x4*)(E + ((size_t)(b*NCH + c))*D_M + d0) = e;
}

// pass 2: sequential combine of chunk carries: S_c = lam^CHK * S_{c-1} + E_c
__global__ void scan2_k(const float* __restrict__ E, float* __restrict__ S,
                        const float* __restrict__ decay){
  const int idx = blockIdx.x*blockDim.x + threadIdx.x;
  if (idx >= BB*(D_M/4)) return;
  const int b  = idx / (D_M/4);
  const int d0 = (idx % (D_M/4))*4;
  const float lam  = decay[d0>>6];
  const float lamT = __expf((float)CHK * __logf(lam));
  f32x4 s = {0.f,0.f,0.f,0.f};
  for (int c=0;c<NCH;c++){
    const size_t o = ((size_t)(b*NCH + c))*D_M + d0;
    f32x4 e = *(const f32x4*)(E + o);
    s = s*lamT + e;
    *(f32x4*)(S + o) = s;
  }
}

// fused: state = local + lam^(i+1)*carry; y = q*state; LayerNorm; *gate; bf16 out (in place over q)
__global__ __launch_bounds__(256) void fuse_ln_k(
  const u16* __restrict__ qb, const u16* __restrict__ locb, const u16* __restrict__ gateb,
  const float* __restrict__ S, const float* __restrict__ decay,
  const float* __restrict__ gamma, const float* __restrict__ beta,
  u16* __restrict__ yout)
{
  const int token = blockIdx.x;
  const int b  = token >> 13;        // L = 8192
  const int t  = token & (LL-1);
  const int c  = t >> 7;             // CHK = 128
  const int ii = t & (CHK-1);
  const int tid = threadIdx.x;
  const int d0 = tid*4;
  const float lam = decay[d0>>6];
  const float pw  = __expf((float)(ii+1) * __logf(lam));
  f32x4 carry = {0.f,0.f,0.f,0.f};
  if (c > 0) carry = *(const f32x4*)(S + ((size_t)(b*NCH + (c-1)))*D_M + d0);
  const size_t base = (size_t)token*D_M + d0;
  s16x4 q4 = *(const s16x4*)(qb + base);
  s16x4 l4 = *(const s16x4*)(locb + base);
  float y[4];
  #pragma unroll
  for (int j=0;j<4;j++)
    y[j] = bf2f((u16)q4[j]) * (bf2f((u16)l4[j]) + pw*carry[j]);
  float sum = y[0]+y[1]+y[2]+y[3];
  float sq  = y[0]*y[0]+y[1]*y[1]+y[2]*y[2]+y[3]*y[3];
  #pragma unroll
  for (int off=32; off>0; off>>=1){
    sum += __shfl_down(sum, off);
    sq  += __shfl_down(sq , off);
  }
  __shared__ float red[10];
  const int wave = tid>>6, lane = tid&63;
  if (lane==0){ red[wave] = sum; red[4+wave] = sq; }
  __syncthreads();
  if (tid==0){
    float ts = red[0]+red[1]+red[2]+red[3];
    float tq = red[4]+red[5]+red[6]+red[7];
    float mu  = ts * (1.f/(float)D_M);
    float var = tq * (1.f/(float)D_M) - mu*mu;
    red[8] = mu;
    red[9] = rsqrtf(var + LN_EPS);
  }
  __syncthreads();
  const float mu = red[8], rstd = red[9];
  f32x4 gm = *(const f32x4*)(gamma + d0);
  f32x4 bt = *(const f32x4*)(beta  + d0);
  s16x4 g4 = *(const s16x4*)(gateb + base);
  s16x4 o;
  #pragma unroll
  for (int j=0;j<4;j++){
    float nn = (y[j] - mu)*rstd*gm[j] + bt[j];
    nn *= bf2f((u16)g4[j]);
    o[j] = (short)f2bf(nn);
  }
  *(s16x4*)(yout + base) = o;
}

extern "C" void kernel_launch(void* const* d_in, const int* in_sizes, int n_in,
                              void* d_out, int out_size, void* d_ws, size_t ws_size,
                              hipStream_t stream)
{
  const float* x     = (const float*)d_in[0];
  const float* decay = (const float*)d_in[1];
  const float* Wq    = (const float*)d_in[2];
  const float* Wv    = (const float*)d_in[3];
  const float* Wg    = (const float*)d_in[4];
  const float* Wo    = (const float*)d_in[5];
  const float* gamma = (const float*)d_in[6];
  const float* beta  = (const float*)d_in[7];
  float* out = (float*)d_out;

  // workspace layout (~280 MB)
  char* ws = (char*)d_ws;
  size_t off = 0;
  const size_t XB = (size_t)MTOT*D_M*sizeof(u16);      // 64 MiB per activation
  const size_t WB = (size_t)D_M*KDIM*sizeof(u16);      // 2 MiB per weight
  const size_t EB = (size_t)BB*NCH*D_M*sizeof(float);  // 1 MiB
  u16* xb  = (u16*)(ws+off); off += XB;
  u16* Wqb = (u16*)(ws+off); off += WB;
  u16* Wvb = (u16*)(ws+off); off += WB;
  u16* Wgb = (u16*)(ws+off); off += WB;
  u16* Wob = (u16*)(ws+off); off += WB;
  u16* qb  = (u16*)(ws+off); off += XB;  // q, then reused as y_ln
  u16* vb  = (u16*)(ws+off); off += XB;  // v, scanned in place to local state
  u16* gb  = (u16*)(ws+off); off += XB;  // silu(x Wg^T)
  float* E = (float*)(ws+off); off += EB;
  float* S = (float*)(ws+off); off += EB;

  conv_f2b_k<<<dim3(4096), 256, 0, stream>>>(x,  xb,  MTOT*D_M/4);
  conv_f2b_k<<<dim3(512),  256, 0, stream>>>(Wq, Wqb, D_M*KDIM/4);
  conv_f2b_k<<<dim3(512),  256, 0, stream>>>(Wv, Wvb, D_M*KDIM/4);
  conv_f2b_k<<<dim3(512),  256, 0, stream>>>(Wg, Wgb, D_M*KDIM/4);
  conv_f2b_k<<<dim3(512),  256, 0, stream>>>(Wo, Wob, D_M*KDIM/4);

  // q / v / gate projections in one launch (z = 0,1,2), silu fused for gate
  gemm_bt<0><<<dim3(MTOT/128, D_M/128, 3), 256, 0, stream>>>(xb, Wqb, Wvb, Wgb, qb, vb, gb);

  scan1_k<<<dim3(NCH, BB), 256, 0, stream>>>(vb, E, decay);
  scan2_k<<<dim3(4), 256, 0, stream>>>(E, S, decay);

  fuse_ln_k<<<dim3(MTOT), 256, 0, stream>>>(qb, vb, gb, S, decay, gamma, beta, qb);

  // out = y_ln @ Wo^T (fp32 output)
  gemm_bt<1><<<dim3(MTOT/128, D_M/128, 1), 256, 0, stream>>>(qb, Wob, Wob, Wob,
                                                             (void*)out, (void*)out, (void*)out);
}

// Round 3
// 420.198 us; speedup vs baseline: 1.1382x; 1.1382x over previous
//
#include <hip/hip_runtime.h>
#include <cstdint>
#include <cstddef>

typedef unsigned short u16;
typedef __attribute__((ext_vector_type(4))) float f32x4;
typedef __attribute__((ext_vector_type(8))) short s16x8;
typedef __attribute__((ext_vector_type(4))) short s16x4;

#define D_M   1024
#define KDIM  1024
#define BB    4
#define LL    8192
#define MTOT  (BB*LL)
#define CHK   64
#define CHK_SH 6
#define NCH   (LL/CHK)
#define NT    (KDIM/64)
#define LN_EPS 1e-5f

static __device__ __forceinline__ float bf2f(u16 u){
  return __uint_as_float(((unsigned)u)<<16);
}
static __device__ __forceinline__ u16 f2bf(float f){
  unsigned u = __float_as_uint(f);
  u += 0x7fffu + ((u>>16)&1u);
  return (u16)(u>>16);
}

// fp32 -> bf16 vectorized convert
__global__ void conv_f2b_k(const float* __restrict__ src, u16* __restrict__ dst, int n4){
  int i = blockIdx.x*blockDim.x + threadIdx.x;
  int stride = gridDim.x*blockDim.x;
  for (; i < n4; i += stride){
    f32x4 f = ((const f32x4*)src)[i];
    s16x4 o;
    o[0]=(short)f2bf(f[0]); o[1]=(short)f2bf(f[1]);
    o[2]=(short)f2bf(f[2]); o[3]=(short)f2bf(f[3]);
    ((s16x4*)dst)[i] = o;
  }
}

// 4 weight matrices in one launch; grid (1024, 4), 256 thr
__global__ void conv_w4_k(const float* __restrict__ s0, const float* __restrict__ s1,
                          const float* __restrict__ s2, const float* __restrict__ s3,
                          u16* __restrict__ d0, u16* __restrict__ d1,
                          u16* __restrict__ d2, u16* __restrict__ d3){
  const float* s; u16* d;
  switch(blockIdx.y){
    case 0: s=s0; d=d0; break;
    case 1: s=s1; d=d1; break;
    case 2: s=s2; d=d2; break;
    default: s=s3; d=d3; break;
  }
  int i = blockIdx.x*blockDim.x + threadIdx.x;
  f32x4 f = ((const f32x4*)s)[i];
  s16x4 o;
  o[0]=(short)f2bf(f[0]); o[1]=(short)f2bf(f[1]);
  o[2]=(short)f2bf(f[2]); o[3]=(short)f2bf(f[3]);
  ((s16x4*)d)[i] = o;
}

// ---------------------------------------------------------------------------
// 256x256 tile, BK=64, 8 waves (2M x 4N), 8-phase schedule with counted vmcnt.
// C[M,N] = A[M,K] @ W[N,K]^T, bf16 in, fp32 acc.
// LDS: As[2][256x64] | Bs[2][256x64] bf16 = 128 KiB, XOR-swizzled 16B chunks:
//   LDS[row][slot] holds global k-chunk kc = slot ^ (row&7); staging writes
//   linearly (global_load_lds) from pre-swizzled global addresses.
// Wave (wm=wave>>2, wn=wave&3) owns C rows {wm*64+[0,64)} U {128+wm*64+[0,64)},
// cols {wn*32+[0,32)} U {128+wn*32+[0,32)}. Phases per K-tile: q0=(mlo,nlo)
// q1=(mlo,nhi) q2=(mhi,nhi) q3=(mhi,nlo). Stage: S(t+1,A1)@q0, S(t+2,A0)@q1,
// S(t+2,B0)@q2, S(t+2,B1)@q3; s_waitcnt vmcnt(6) at q3 (vmcnt(0) last 2 tiles).
// LDS elem offsets: A0=cur*16384, A1=+8192, B0=32768+cur*16384, B1=+8192.
// ---------------------------------------------------------------------------
template<int F32OUT>
__global__ __launch_bounds__(512,2) void gemm256(
    const u16* __restrict__ A,
    const u16* __restrict__ W0, const u16* __restrict__ W1, const u16* __restrict__ W2,
    void* __restrict__ O0, void* __restrict__ O1, void* __restrict__ O2)
{
  __shared__ __align__(16) u16 smem[65536];   // 128 KiB

  const int mode = blockIdx.z;
  const u16* W = (mode==0)? W0 : ((mode==1)? W1 : W2);
  void* Ov     = (mode==0)? O0 : ((mode==1)? O1 : O2);

  const int tid  = threadIdx.x;
  const int wave = tid>>6, lane = tid&63;
  const int bm = blockIdx.x*256, bn = blockIdx.y*256;

  // staging geometry (per thread, both 16B loads of a half-tile)
  const int rr = tid>>3;                          // row 0..63 (j=0); j=1 adds 64
  const int kk = (((tid&7) ^ (rr&7)))*8;          // swizzled k-chunk, u16 elems
  const int ldw = wave*512;                       // j=0 LDS elem base (wave-uniform)

  #define STAGE(GBASE, LOFF) do {                                                       \
    const u16* _g = (GBASE) + (size_t)rr*KDIM + kk;                                     \
    __builtin_amdgcn_global_load_lds(                                                   \
      (const __attribute__((address_space(1))) void*)(_g),                              \
      (__attribute__((address_space(3))) void*)(smem + (LOFF) + ldw), 16, 0, 0);        \
    __builtin_amdgcn_global_load_lds(                                                   \
      (const __attribute__((address_space(1))) void*)(_g + (size_t)64*KDIM),            \
      (__attribute__((address_space(3))) void*)(smem + (LOFF) + 4096 + ldw), 16, 0, 0); \
  } while(0)

  // read-side fragment offsets (u16 elems), rows*64 + slot*8
  const int lr = lane&15, lk = lane>>4;
  const int wm = wave>>2, wn = wave&3;
  int aoff[4][2], boff[2][2];                     // mlo/nlo bases; mhi/nhi = +8192
  #pragma unroll
  for (int mi=0; mi<4; ++mi)
    #pragma unroll
    for (int kp=0; kp<2; ++kp)
      aoff[mi][kp] = (wm*64 + mi*16 + lr)*64 + (((kp*4+lk) ^ (lr&7)))*8;
  #pragma unroll
  for (int ni=0; ni<2; ++ni)
    #pragma unroll
    for (int kp=0; kp<2; ++kp)
      boff[ni][kp] = (wn*32 + ni*16 + lr)*64 + (((kp*4+lk) ^ (lr&7)))*8;

  const f32x4 fzero = {0.f,0.f,0.f,0.f};
  f32x4 acc[8][4];
  #pragma unroll
  for (int i=0;i<8;i++)
    #pragma unroll
    for (int j=0;j<4;j++)
      acc[i][j] = fzero;

  const u16* Abase = A + (size_t)bm*KDIM;
  const u16* Wbase = W + (size_t)bn*KDIM;

  // ---- prologue: S(0,A0,B0,B1,A1); S(1,A0,B0,B1); wait S(0,*)
  STAGE(Abase,                    0);          // t0 A0
  STAGE(Wbase,                    32768);      // t0 B0
  STAGE(Wbase + (size_t)128*KDIM, 32768+8192); // t0 B1
  STAGE(Abase + (size_t)128*KDIM, 8192);       // t0 A1
  STAGE(Abase + 64,                    16384);       // t1 A0
  STAGE(Wbase + 64,                    49152);       // t1 B0
  STAGE(Wbase + (size_t)128*KDIM + 64, 49152+8192);  // t1 B1
  asm volatile("s_waitcnt vmcnt(6)" ::: "memory");
  __builtin_amdgcn_s_barrier();

  s16x8 afr[4][2], blo[2][2], bhi[2][2];

  for (int kt=0; kt<NT; ++kt){
    const int cur = kt&1, nxt = cur^1;
    const int curA = cur*16384;
    const int curB = 32768 + cur*16384;
    const int nxtA = nxt*16384;
    const u16* Ac = smem + curA;
    const u16* Bc = smem + curB;

    // ---- phase 0: q(mlo,nlo); stage S(t+1, A1)
    #pragma unroll
    for (int mi=0; mi<4; ++mi)
      #pragma unroll
      for (int kp=0; kp<2; ++kp)
        afr[mi][kp] = *(const s16x8*)(Ac + aoff[mi][kp]);
    #pragma unroll
    for (int ni=0; ni<2; ++ni)
      #pragma unroll
      for (int kp=0; kp<2; ++kp)
        blo[ni][kp] = *(const s16x8*)(Bc + boff[ni][kp]);
    if (kt+1 < NT) STAGE(Abase + (size_t)128*KDIM + (kt+1)*64, nxtA + 8192);
    __builtin_amdgcn_s_barrier();
    __builtin_amdgcn_s_setprio(1);
    #pragma unroll
    for (int mi=0; mi<4; ++mi)
      #pragma unroll
      for (int ni=0; ni<2; ++ni)
        #pragma unroll
        for (int kp=0; kp<2; ++kp)
          acc[mi][ni] = __builtin_amdgcn_mfma_f32_16x16x32_bf16(afr[mi][kp], blo[ni][kp], acc[mi][ni], 0,0,0);
    __builtin_amdgcn_s_setprio(0);
    __builtin_amdgcn_s_barrier();

    // ---- phase 1: q(mlo,nhi); stage S(t+2, A0)
    #pragma unroll
    for (int ni=0; ni<2; ++ni)
      #pragma unroll
      for (int kp=0; kp<2; ++kp)
        bhi[ni][kp] = *(const s16x8*)(Bc + 8192 + boff[ni][kp]);
    if (kt+2 < NT) STAGE(Abase + (kt+2)*64, curA);
    __builtin_amdgcn_s_barrier();
    __builtin_amdgcn_s_setprio(1);
    #pragma unroll
    for (int mi=0; mi<4; ++mi)
      #pragma unroll
      for (int ni=0; ni<2; ++ni)
        #pragma unroll
        for (int kp=0; kp<2; ++kp)
          acc[mi][2+ni] = __builtin_amdgcn_mfma_f32_16x16x32_bf16(afr[mi][kp], bhi[ni][kp], acc[mi][2+ni], 0,0,0);
    __builtin_amdgcn_s_setprio(0);
    __builtin_amdgcn_s_barrier();

    // ---- phase 2: q(mhi,nhi); stage S(t+2, B0)
    #pragma unroll
    for (int mi=0; mi<4; ++mi)
      #pragma unroll
      for (int kp=0; kp<2; ++kp)
        afr[mi][kp] = *(const s16x8*)(Ac + 8192 + aoff[mi][kp]);
    if (kt+2 < NT) STAGE(Wbase + (kt+2)*64, curB);
    __builtin_amdgcn_s_barrier();
    __builtin_amdgcn_s_setprio(1);
    #pragma unroll
    for (int mi=0; mi<4; ++mi)
      #pragma unroll
      for (int ni=0; ni<2; ++ni)
        #pragma unroll
        for (int kp=0; kp<2; ++kp)
          acc[4+mi][2+ni] = __builtin_amdgcn_mfma_f32_16x16x32_bf16(afr[mi][kp], bhi[ni][kp], acc[4+mi][2+ni], 0,0,0);
    __builtin_amdgcn_s_setprio(0);
    __builtin_amdgcn_s_barrier();

    // ---- phase 3: q(mhi,nlo); stage S(t+2, B1); counted vmcnt
    if (kt+2 < NT) STAGE(Wbase + (size_t)128*KDIM + (kt+2)*64, curB + 8192);
    __builtin_amdgcn_s_barrier();
    __builtin_amdgcn_s_setprio(1);
    #pragma unroll
    for (int mi=0; mi<4; ++mi)
      #pragma unroll
      for (int ni=0; ni<2; ++ni)
        #pragma unroll
        for (int kp=0; kp<2; ++kp)
          acc[4+mi][ni] = __builtin_amdgcn_mfma_f32_16x16x32_bf16(afr[mi][kp], blo[ni][kp], acc[4+mi][ni], 0,0,0);
    __builtin_amdgcn_s_setprio(0);
    if (kt < NT-2) { asm volatile("s_waitcnt vmcnt(6)" ::: "memory"); }
    else           { asm volatile("s_waitcnt vmcnt(0)" ::: "memory"); }
    __builtin_amdgcn_s_barrier();
  }
  #undef STAGE

  // ---- epilogue: C/D layout col=lane&15, row=(lane>>4)*4+reg
  const int rq = (lane>>4)*4;
  const int cl = lane&15;
  if (F32OUT){
    float* O = (float*)Ov;
    #pragma unroll
    for (int mi=0; mi<8; ++mi){
      const int grow = bm + (mi>>2)*128 + wm*64 + (mi&3)*16 + rq;
      #pragma unroll
      for (int ni=0; ni<4; ++ni){
        const int gcol = bn + (ni>>1)*128 + wn*32 + (ni&1)*16 + cl;
        #pragma unroll
        for (int r=0;r<4;r++)
          O[(size_t)(grow + r)*D_M + gcol] = acc[mi][ni][r];
      }
    }
  } else {
    u16* O = (u16*)Ov;
    const bool do_silu = (mode==2);
    #pragma unroll
    for (int mi=0; mi<8; ++mi){
      const int grow = bm + (mi>>2)*128 + wm*64 + (mi&3)*16 + rq;
      #pragma unroll
      for (int ni=0; ni<4; ++ni){
        const int gcol = bn + (ni>>1)*128 + wn*32 + (ni&1)*16 + cl;
        #pragma unroll
        for (int r=0;r<4;r++){
          float vv = acc[mi][ni][r];
          if (do_silu) vv = vv / (1.f + __expf(-vv));
          O[(size_t)(grow + r)*D_M + gcol] = f2bf(vv);
        }
      }
    }
  }
}

// pass 1: per-chunk local inclusive scan, in place over v; chunk-end -> E (fp32)
__global__ __launch_bounds__(256) void scan1_k(u16* __restrict__ v, float* __restrict__ E,
                                               const float* __restrict__ decay){
  const int c = blockIdx.x, b = blockIdx.y;
  const int d0 = threadIdx.x*4;
  const float lam = decay[d0>>6];
  float s0=0.f,s1=0.f,s2=0.f,s3=0.f;
  u16* p = v + ((size_t)b*LL + (size_t)c*CHK)*D_M + d0;
  for (int i=0;i<CHK;i++){
    s16x4 x = *(const s16x4*)p;
    s0 = fmaf(s0, lam, bf2f((u16)x[0]));
    s1 = fmaf(s1, lam, bf2f((u16)x[1]));
    s2 = fmaf(s2, lam, bf2f((u16)x[2]));
    s3 = fmaf(s3, lam, bf2f((u16)x[3]));
    s16x4 o;
    o[0]=(short)f2bf(s0); o[1]=(short)f2bf(s1);
    o[2]=(short)f2bf(s2); o[3]=(short)f2bf(s3);
    *(s16x4*)p = o;
    p += D_M;
  }
  f32x4 e = {s0,s1,s2,s3};
  *(f32x4*)(E + ((size_t)(b*NCH + c))*D_M + d0) = e;
}

// pass 2: sequential combine of chunk carries: S_c = lam^CHK * S_{c-1} + E_c
__global__ void scan2_k(const float* __restrict__ E, float* __restrict__ S,
                        const float* __restrict__ decay){
  const int idx = blockIdx.x*blockDim.x + threadIdx.x;
  if (idx >= BB*(D_M/4)) return;
  const int b  = idx / (D_M/4);
  const int d0 = (idx % (D_M/4))*4;
  const float lam  = decay[d0>>6];
  const float lamT = __expf((float)CHK * __logf(lam));
  f32x4 s = {0.f,0.f,0.f,0.f};
  for (int c=0;c<NCH;c++){
    const size_t o = ((size_t)(b*NCH + c))*D_M + d0;
    f32x4 e = *(const f32x4*)(E + o);
    s = s*lamT + e;
    *(f32x4*)(S + o) = s;
  }
}

// fused: state = local + lam^(i+1)*carry; y = q*state; LayerNorm; *gate; bf16 out
__global__ __launch_bounds__(256) void fuse_ln_k(
  const u16* __restrict__ qb, const u16* __restrict__ locb, const u16* __restrict__ gateb,
  const float* __restrict__ S, const float* __restrict__ decay,
  const float* __restrict__ gamma, const float* __restrict__ beta,
  u16* __restrict__ yout)
{
  const int token = blockIdx.x;
  const int b  = token >> 13;        // L = 8192
  const int t  = token & (LL-1);
  const int c  = t >> CHK_SH;
  const int ii = t & (CHK-1);
  const int tid = threadIdx.x;
  const int d0 = tid*4;
  const float lam = decay[d0>>6];
  const float pw  = __expf((float)(ii+1) * __logf(lam));
  f32x4 carry = {0.f,0.f,0.f,0.f};
  if (c > 0) carry = *(const f32x4*)(S + ((size_t)(b*NCH + (c-1)))*D_M + d0);
  const size_t base = (size_t)token*D_M + d0;
  s16x4 q4 = *(const s16x4*)(qb + base);
  s16x4 l4 = *(const s16x4*)(locb + base);
  float y[4];
  #pragma unroll
  for (int j=0;j<4;j++)
    y[j] = bf2f((u16)q4[j]) * (bf2f((u16)l4[j]) + pw*carry[j]);
  float sum = y[0]+y[1]+y[2]+y[3];
  float sq  = y[0]*y[0]+y[1]*y[1]+y[2]*y[2]+y[3]*y[3];
  #pragma unroll
  for (int off=32; off>0; off>>=1){
    sum += __shfl_down(sum, off);
    sq  += __shfl_down(sq , off);
  }
  __shared__ float red[10];
  const int wave = tid>>6, lane = tid&63;
  if (lane==0){ red[wave] = sum; red[4+wave] = sq; }
  __syncthreads();
  if (tid==0){
    float ts = red[0]+red[1]+red[2]+red[3];
    float tq = red[4]+red[5]+red[6]+red[7];
    float mu  = ts * (1.f/(float)D_M);
    float var = tq * (1.f/(float)D_M) - mu*mu;
    red[8] = mu;
    red[9] = rsqrtf(var + LN_EPS);
  }
  __syncthreads();
  const float mu = red[8], rstd = red[9];
  f32x4 gm = *(const f32x4*)(gamma + d0);
  f32x4 bt = *(const f32x4*)(beta  + d0);
  s16x4 g4 = *(const s16x4*)(gateb + base);
  s16x4 o;
  #pragma unroll
  for (int j=0;j<4;j++){
    float nn = (y[j] - mu)*rstd*gm[j] + bt[j];
    nn *= bf2f((u16)g4[j]);
    o[j] = (short)f2bf(nn);
  }
  *(s16x4*)(yout + base) = o;
}

extern "C" void kernel_launch(void* const* d_in, const int* in_sizes, int n_in,
                              void* d_out, int out_size, void* d_ws, size_t ws_size,
                              hipStream_t stream)
{
  const float* x     = (const float*)d_in[0];
  const float* decay = (const float*)d_in[1];
  const float* Wq    = (const float*)d_in[2];
  const float* Wv    = (const float*)d_in[3];
  const float* Wg    = (const float*)d_in[4];
  const float* Wo    = (const float*)d_in[5];
  const float* gamma = (const float*)d_in[6];
  const float* beta  = (const float*)d_in[7];
  float* out = (float*)d_out;

  char* ws = (char*)d_ws;
  size_t off = 0;
  const size_t XB = (size_t)MTOT*D_M*sizeof(u16);      // 64 MiB per activation
  const size_t WB = (size_t)D_M*KDIM*sizeof(u16);      // 2 MiB per weight
  const size_t EB = (size_t)BB*NCH*D_M*sizeof(float);  // 2 MiB
  u16* xb  = (u16*)(ws+off); off += XB;
  u16* Wqb = (u16*)(ws+off); off += WB;
  u16* Wvb = (u16*)(ws+off); off += WB;
  u16* Wgb = (u16*)(ws+off); off += WB;
  u16* Wob = (u16*)(ws+off); off += WB;
  u16* qb  = (u16*)(ws+off); off += XB;  // q, then reused as y_ln
  u16* vb  = (u16*)(ws+off); off += XB;  // v, scanned in place to local state
  u16* gb  = (u16*)(ws+off); off += XB;  // silu(x Wg^T)
  float* E = (float*)(ws+off); off += EB;
  float* S = (float*)(ws+off); off += EB;

  conv_f2b_k<<<dim3(2048), 256, 0, stream>>>(x,  xb,  MTOT*D_M/4);
  conv_w4_k<<<dim3(1024,4), 256, 0, stream>>>(Wq, Wv, Wg, Wo, Wqb, Wvb, Wgb, Wob);

  // q / v / gate projections in one launch (z = 0,1,2), silu fused for gate
  gemm256<0><<<dim3(MTOT/256, D_M/256, 3), 512, 0, stream>>>(xb, Wqb, Wvb, Wgb, qb, vb, gb);

  scan1_k<<<dim3(NCH, BB), 256, 0, stream>>>(vb, E, decay);
  scan2_k<<<dim3(4), 256, 0, stream>>>(E, S, decay);

  fuse_ln_k<<<dim3(MTOT), 256, 0, stream>>>(qb, vb, gb, S, decay, gamma, beta, qb);

  // out = y_ln @ Wo^T (fp32 output)
  gemm256<1><<<dim3(MTOT/256, D_M/256, 1), 512, 0, stream>>>(qb, Wob, Wob, Wob,
                                                             (void*)out, (void*)out, (void*)out);
}

// Round 4
// 417.458 us; speedup vs baseline: 1.1457x; 1.0066x over previous
//
#include <hip/hip_runtime.h>
#include <cstdint>
#include <cstddef>

typedef unsigned short u16;
typedef __attribute__((ext_vector_type(4))) float f32x4;
typedef __attribute__((ext_vector_type(8))) short s16x8;
typedef __attribute__((ext_vector_type(4))) short s16x4;

#define D_M   1024
#define KDIM  1024
#define BB    4
#define LL    8192
#define MTOT  (BB*LL)
#define CHK   64
#define CHK_SH 6
#define NCH   (LL/CHK)
#define NT    (KDIM/64)
#define LN_EPS 1e-5f

static __device__ __forceinline__ float bf2f(u16 u){
  return __uint_as_float(((unsigned)u)<<16);
}
static __device__ __forceinline__ u16 f2bf(float f){
  unsigned u = __float_as_uint(f);
  u += 0x7fffu + ((u>>16)&1u);
  return (u16)(u>>16);
}

// inline-asm LDS read: compiler cannot see the smem dependency, so it cannot
// insert conservative vmcnt() drains against outstanding global_load_lds DMA.
template<int IMM>
static __device__ __forceinline__ s16x8 dsr(uint32_t a){
  s16x8 d;
  asm volatile("ds_read_b128 %0, %1 offset:%c2" : "=v"(d) : "v"(a), "i"(IMM));
  return d;
}

// fp32 -> bf16 vectorized convert
__global__ void conv_f2b_k(const float* __restrict__ src, u16* __restrict__ dst, int n4){
  int i = blockIdx.x*blockDim.x + threadIdx.x;
  int stride = gridDim.x*blockDim.x;
  for (; i < n4; i += stride){
    f32x4 f = ((const f32x4*)src)[i];
    s16x4 o;
    o[0]=(short)f2bf(f[0]); o[1]=(short)f2bf(f[1]);
    o[2]=(short)f2bf(f[2]); o[3]=(short)f2bf(f[3]);
    ((s16x4*)dst)[i] = o;
  }
}

// 4 weight matrices in one launch; grid (1024, 4), 256 thr
__global__ void conv_w4_k(const float* __restrict__ s0, const float* __restrict__ s1,
                          const float* __restrict__ s2, const float* __restrict__ s3,
                          u16* __restrict__ d0, u16* __restrict__ d1,
                          u16* __restrict__ d2, u16* __restrict__ d3){
  const float* s; u16* d;
  switch(blockIdx.y){
    case 0: s=s0; d=d0; break;
    case 1: s=s1; d=d1; break;
    case 2: s=s2; d=d2; break;
    default: s=s3; d=d3; break;
  }
  int i = blockIdx.x*blockDim.x + threadIdx.x;
  f32x4 f = ((const f32x4*)s)[i];
  s16x4 o;
  o[0]=(short)f2bf(f[0]); o[1]=(short)f2bf(f[1]);
  o[2]=(short)f2bf(f[2]); o[3]=(short)f2bf(f[3]);
  ((s16x4*)d)[i] = o;
}

// ---------------------------------------------------------------------------
// 256x256 tile, BK=64, 8 waves (2M x 4N), 8-phase schedule, counted vmcnt.
// LDS 128 KiB: A [0,64K): cur*32768B + hi*16384B; B [64K,128K): same.
// XOR swizzle: LDS[row][slot] holds k-chunk kc = slot ^ (row&7) (16B units).
// All LDS fragment reads are inline-asm ds_read_b128; cur/hi/mi folded into
// offset immediates; K-loop unrolled x2 so cur is compile-time.
// ---------------------------------------------------------------------------
template<int F32OUT>
__global__ __launch_bounds__(512,2) void gemm256(
    const u16* __restrict__ A,
    const u16* __restrict__ W0, const u16* __restrict__ W1, const u16* __restrict__ W2,
    void* __restrict__ O0, void* __restrict__ O1, void* __restrict__ O2)
{
  __shared__ __align__(16) u16 smem[65536];   // 128 KiB

  const int mode = blockIdx.z;
  const u16* W = (mode==0)? W0 : ((mode==1)? W1 : W2);
  void* Ov     = (mode==0)? O0 : ((mode==1)? O1 : O2);

  const int tid  = threadIdx.x;
  const int wave = tid>>6, lane = tid&63;
  const int bm = blockIdx.x*256, bn = blockIdx.y*256;

  // staging geometry (per thread, both 16B loads of a half-tile)
  const int rr = tid>>3;                          // row 0..63 (j=0); j=1 adds 64
  const int kk = (((tid&7) ^ (rr&7)))*8;          // swizzled k-chunk, u16 elems
  const int ldw = wave*512;                       // j=0 LDS elem base (wave-uniform)

  #define STAGE(GBASE, LOFF) do {                                                       \
    const u16* _g = (GBASE) + (size_t)rr*KDIM + kk;                                     \
    __builtin_amdgcn_global_load_lds(                                                   \
      (const __attribute__((address_space(1))) void*)(_g),                              \
      (__attribute__((address_space(3))) void*)(smem + (LOFF) + ldw), 16, 0, 0);        \
    __builtin_amdgcn_global_load_lds(                                                   \
      (const __attribute__((address_space(1))) void*)(_g + (size_t)64*KDIM),            \
      (__attribute__((address_space(3))) void*)(smem + (LOFF) + 4096 + ldw), 16, 0, 0); \
  } while(0)

  // read-side base addresses (bytes, 32-bit LDS)
  const uint32_t smem_base =
    (uint32_t)(uintptr_t)((__attribute__((address_space(3))) u16*)smem);
  const int lr = lane&15, lk = lane>>4;
  const int wm = wave>>2, wn = wave&3;
  const uint32_t vA0 = smem_base + (uint32_t)((((wm*64+lr)*64) + (( lk   )^(lr&7))*8)<<1);
  const uint32_t vA1 = smem_base + (uint32_t)((((wm*64+lr)*64) + ((4+lk  )^(lr&7))*8)<<1);
  const uint32_t vB0 = smem_base + 65536u + (uint32_t)((((wn*32+lr)*64) + (( lk )^(lr&7))*8)<<1);
  const uint32_t vB1 = smem_base + 65536u + (uint32_t)((((wn*32+lr)*64) + ((4+lk)^(lr&7))*8)<<1);

  const f32x4 fzero = {0.f,0.f,0.f,0.f};
  f32x4 acc[8][4];
  #pragma unroll
  for (int i=0;i<8;i++)
    #pragma unroll
    for (int j=0;j<4;j++)
      acc[i][j] = fzero;

  const u16* Abase = A + (size_t)bm*KDIM;
  const u16* Wbase = W + (size_t)bn*KDIM;

  // ---- prologue: S(0,A0,B0,B1,A1); S(1,A0,B0,B1); wait S(0,*)
  STAGE(Abase,                    0);          // t0 A0
  STAGE(Wbase,                    32768);      // t0 B0
  STAGE(Wbase + (size_t)128*KDIM, 32768+8192); // t0 B1
  STAGE(Abase + (size_t)128*KDIM, 8192);       // t0 A1
  STAGE(Abase + 64,                    16384);       // t1 A0
  STAGE(Wbase + 64,                    49152);       // t1 B0
  STAGE(Wbase + (size_t)128*KDIM + 64, 49152+8192);  // t1 B1
  asm volatile("s_waitcnt vmcnt(6)" ::: "memory");
  __builtin_amdgcn_s_barrier();

  s16x8 afr[4][2], blo[2][2], bhi[2][2];

  #define LDA8(CUR,HI) \
    afr[0][0]=dsr<(CUR)*32768+(HI)*16384+0   >(vA0); afr[0][1]=dsr<(CUR)*32768+(HI)*16384+0   >(vA1); \
    afr[1][0]=dsr<(CUR)*32768+(HI)*16384+2048>(vA0); afr[1][1]=dsr<(CUR)*32768+(HI)*16384+2048>(vA1); \
    afr[2][0]=dsr<(CUR)*32768+(HI)*16384+4096>(vA0); afr[2][1]=dsr<(CUR)*32768+(HI)*16384+4096>(vA1); \
    afr[3][0]=dsr<(CUR)*32768+(HI)*16384+6144>(vA0); afr[3][1]=dsr<(CUR)*32768+(HI)*16384+6144>(vA1);

  #define LDB4(DST,CUR,HI) \
    DST[0][0]=dsr<(CUR)*32768+(HI)*16384+0   >(vB0); DST[0][1]=dsr<(CUR)*32768+(HI)*16384+0   >(vB1); \
    DST[1][0]=dsr<(CUR)*32768+(HI)*16384+2048>(vB0); DST[1][1]=dsr<(CUR)*32768+(HI)*16384+2048>(vB1);

  #define LGKM_FENCE() do { \
    asm volatile("s_waitcnt lgkmcnt(0)" ::: "memory"); \
    __builtin_amdgcn_sched_barrier(0); \
  } while(0)

  #define MM16(AI0, NI0, BFR) \
    _Pragma("unroll") \
    for (int mi=0; mi<4; ++mi) \
      _Pragma("unroll") \
      for (int ni=0; ni<2; ++ni) \
        _Pragma("unroll") \
        for (int kp=0; kp<2; ++kp) \
          acc[(AI0)+mi][(NI0)+ni] = __builtin_amdgcn_mfma_f32_16x16x32_bf16( \
            afr[mi][kp], BFR[ni][kp], acc[(AI0)+mi][(NI0)+ni], 0,0,0);

  #define TILE(KT, CUR) do {                                                       \
    /* phase 0: q(mlo,nlo); stage S(t+1, A1) */                                    \
    LDA8(CUR,0)                                                                    \
    LDB4(blo,CUR,0)                                                                \
    if ((KT)+1 < NT) STAGE(Abase + (size_t)128*KDIM + ((KT)+1)*64,                 \
                           ((CUR)^1)*16384 + 8192);                                \
    __builtin_amdgcn_s_barrier();                                                  \
    LGKM_FENCE();                                                                  \
    __builtin_amdgcn_s_setprio(1);                                                 \
    MM16(0,0,blo)                                                                  \
    __builtin_amdgcn_s_setprio(0);                                                 \
    __builtin_amdgcn_s_barrier();                                                  \
    /* phase 1: q(mlo,nhi); stage S(t+2, A0) */                                    \
    LDB4(bhi,CUR,1)                                                                \
    if ((KT)+2 < NT) STAGE(Abase + ((KT)+2)*64, (CUR)*16384);                      \
    __builtin_amdgcn_s_barrier();                                                  \
    LGKM_FENCE();                                                                  \
    __builtin_amdgcn_s_setprio(1);                                                 \
    MM16(0,2,bhi)                                                                  \
    __builtin_amdgcn_s_setprio(0);                                                 \
    __builtin_amdgcn_s_barrier();                                                  \
    /* phase 2: q(mhi,nhi); stage S(t+2, B0) */                                    \
    LDA8(CUR,1)                                                                    \
    if ((KT)+2 < NT) STAGE(Wbase + ((KT)+2)*64, 32768 + (CUR)*16384);              \
    __builtin_amdgcn_s_barrier();                                                  \
    LGKM_FENCE();                                                                  \
    __builtin_amdgcn_s_setprio(1);                                                 \
    MM16(4,2,bhi)                                                                  \
    __builtin_amdgcn_s_setprio(0);                                                 \
    __builtin_amdgcn_s_barrier();                                                  \
    /* phase 3: q(mhi,nlo); stage S(t+2, B1); counted vmcnt */                     \
    if ((KT)+2 < NT) STAGE(Wbase + (size_t)128*KDIM + ((KT)+2)*64,                 \
                           32768 + (CUR)*16384 + 8192);                            \
    __builtin_amdgcn_s_barrier();                                                  \
    __builtin_amdgcn_s_setprio(1);                                                 \
    MM16(4,0,blo)                                                                  \
    __builtin_amdgcn_s_setprio(0);                                                 \
    if ((KT) < NT-2) { asm volatile("s_waitcnt vmcnt(6)" ::: "memory"); }          \
    else             { asm volatile("s_waitcnt vmcnt(0)" ::: "memory"); }          \
    __builtin_amdgcn_s_barrier();                                                  \
  } while(0)

  for (int kt=0; kt<NT; kt+=2){
    TILE(kt,   0);
    TILE(kt+1, 1);
  }
  #undef TILE
  #undef MM16
  #undef LGKM_FENCE
  #undef LDB4
  #undef LDA8
  #undef STAGE

  // ---- epilogue: C/D layout col=lane&15, row=(lane>>4)*4+reg
  const int rq = (lane>>4)*4;
  const int cl = lane&15;
  if (F32OUT){
    float* O = (float*)Ov;
    #pragma unroll
    for (int mi=0; mi<8; ++mi){
      const int grow = bm + (mi>>2)*128 + wm*64 + (mi&3)*16 + rq;
      #pragma unroll
      for (int ni=0; ni<4; ++ni){
        const int gcol = bn + (ni>>1)*128 + wn*32 + (ni&1)*16 + cl;
        #pragma unroll
        for (int r=0;r<4;r++)
          O[(size_t)(grow + r)*D_M + gcol] = acc[mi][ni][r];
      }
    }
  } else {
    u16* O = (u16*)Ov;
    const bool do_silu = (mode==2);
    #pragma unroll
    for (int mi=0; mi<8; ++mi){
      const int grow = bm + (mi>>2)*128 + wm*64 + (mi&3)*16 + rq;
      #pragma unroll
      for (int ni=0; ni<4; ++ni){
        const int gcol = bn + (ni>>1)*128 + wn*32 + (ni&1)*16 + cl;
        #pragma unroll
        for (int r=0;r<4;r++){
          float vv = acc[mi][ni][r];
          if (do_silu) vv = vv / (1.f + __expf(-vv));
          O[(size_t)(grow + r)*D_M + gcol] = f2bf(vv);
        }
      }
    }
  }
}

// pass 1: per-chunk local inclusive scan, in place over v; chunk-end -> E (fp32)
__global__ __launch_bounds__(256) void scan1_k(u16* __restrict__ v, float* __restrict__ E,
                                               const float* __restrict__ decay){
  const int c = blockIdx.x, b = blockIdx.y;
  const int d0 = threadIdx.x*4;
  const float lam = decay[d0>>6];
  float s0=0.f,s1=0.f,s2=0.f,s3=0.f;
  u16* p = v + ((size_t)b*LL + (size_t)c*CHK)*D_M + d0;
  for (int i=0;i<CHK;i++){
    s16x4 x = *(const s16x4*)p;
    s0 = fmaf(s0, lam, bf2f((u16)x[0]));
    s1 = fmaf(s1, lam, bf2f((u16)x[1]));
    s2 = fmaf(s2, lam, bf2f((u16)x[2]));
    s3 = fmaf(s3, lam, bf2f((u16)x[3]));
    s16x4 o;
    o[0]=(short)f2bf(s0); o[1]=(short)f2bf(s1);
    o[2]=(short)f2bf(s2); o[3]=(short)f2bf(s3);
    *(s16x4*)p = o;
    p += D_M;
  }
  f32x4 e = {s0,s1,s2,s3};
  *(f32x4*)(E + ((size_t)(b*NCH + c))*D_M + d0) = e;
}

// pass 2: sequential combine of chunk carries: S_c = lam^CHK * S_{c-1} + E_c
__global__ void scan2_k(const float* __restrict__ E, float* __restrict__ S,
                        const float* __restrict__ decay){
  const int idx = blockIdx.x*blockDim.x + threadIdx.x;
  if (idx >= BB*(D_M/4)) return;
  const int b  = idx / (D_M/4);
  const int d0 = (idx % (D_M/4))*4;
  const float lam  = decay[d0>>6];
  const float lamT = __expf((float)CHK * __logf(lam));
  f32x4 s = {0.f,0.f,0.f,0.f};
  for (int c=0;c<NCH;c++){
    const size_t o = ((size_t)(b*NCH + c))*D_M + d0;
    f32x4 e = *(const f32x4*)(E + o);
    s = s*lamT + e;
    *(f32x4*)(S + o) = s;
  }
}

// fused: state = local + lam^(i+1)*carry; y = q*state; LayerNorm; *gate; bf16 out
__global__ __launch_bounds__(256) void fuse_ln_k(
  const u16* __restrict__ qb, const u16* __restrict__ locb, const u16* __restrict__ gateb,
  const float* __restrict__ S, const float* __restrict__ decay,
  const float* __restrict__ gamma, const float* __restrict__ beta,
  u16* __restrict__ yout)
{
  const int token = blockIdx.x;
  const int b  = token >> 13;        // L = 8192
  const int t  = token & (LL-1);
  const int c  = t >> CHK_SH;
  const int ii = t & (CHK-1);
  const int tid = threadIdx.x;
  const int d0 = tid*4;
  const float lam = decay[d0>>6];
  const float pw  = __expf((float)(ii+1) * __logf(lam));
  f32x4 carry = {0.f,0.f,0.f,0.f};
  if (c > 0) carry = *(const f32x4*)(S + ((size_t)(b*NCH + (c-1)))*D_M + d0);
  const size_t base = (size_t)token*D_M + d0;
  s16x4 q4 = *(const s16x4*)(qb + base);
  s16x4 l4 = *(const s16x4*)(locb + base);
  float y[4];
  #pragma unroll
  for (int j=0;j<4;j++)
    y[j] = bf2f((u16)q4[j]) * (bf2f((u16)l4[j]) + pw*carry[j]);
  float sum = y[0]+y[1]+y[2]+y[3];
  float sq  = y[0]*y[0]+y[1]*y[1]+y[2]*y[2]+y[3]*y[3];
  #pragma unroll
  for (int off=32; off>0; off>>=1){
    sum += __shfl_down(sum, off);
    sq  += __shfl_down(sq , off);
  }
  __shared__ float red[10];
  const int wave = tid>>6, lane = tid&63;
  if (lane==0){ red[wave] = sum; red[4+wave] = sq; }
  __syncthreads();
  if (tid==0){
    float ts = red[0]+red[1]+red[2]+red[3];
    float tq = red[4]+red[5]+red[6]+red[7];
    float mu  = ts * (1.f/(float)D_M);
    float var = tq * (1.f/(float)D_M) - mu*mu;
    red[8] = mu;
    red[9] = rsqrtf(var + LN_EPS);
  }
  __syncthreads();
  const float mu = red[8], rstd = red[9];
  f32x4 gm = *(const f32x4*)(gamma + d0);
  f32x4 bt = *(const f32x4*)(beta  + d0);
  s16x4 g4 = *(const s16x4*)(gateb + base);
  s16x4 o;
  #pragma unroll
  for (int j=0;j<4;j++){
    float nn = (y[j] - mu)*rstd*gm[j] + bt[j];
    nn *= bf2f((u16)g4[j]);
    o[j] = (short)f2bf(nn);
  }
  *(s16x4*)(yout + base) = o;
}

extern "C" void kernel_launch(void* const* d_in, const int* in_sizes, int n_in,
                              void* d_out, int out_size, void* d_ws, size_t ws_size,
                              hipStream_t stream)
{
  const float* x     = (const float*)d_in[0];
  const float* decay = (const float*)d_in[1];
  const float* Wq    = (const float*)d_in[2];
  const float* Wv    = (const float*)d_in[3];
  const float* Wg    = (const float*)d_in[4];
  const float* Wo    = (const float*)d_in[5];
  const float* gamma = (const float*)d_in[6];
  const float* beta  = (const float*)d_in[7];
  float* out = (float*)d_out;

  char* ws = (char*)d_ws;
  size_t off = 0;
  const size_t XB = (size_t)MTOT*D_M*sizeof(u16);      // 64 MiB per activation
  const size_t WB = (size_t)D_M*KDIM*sizeof(u16);      // 2 MiB per weight
  const size_t EB = (size_t)BB*NCH*D_M*sizeof(float);  // 2 MiB
  u16* xb  = (u16*)(ws+off); off += XB;
  u16* Wqb = (u16*)(ws+off); off += WB;
  u16* Wvb = (u16*)(ws+off); off += WB;
  u16* Wgb = (u16*)(ws+off); off += WB;
  u16* Wob = (u16*)(ws+off); off += WB;
  u16* qb  = (u16*)(ws+off); off += XB;  // q, then reused as y_ln
  u16* vb  = (u16*)(ws+off); off += XB;  // v, scanned in place to local state
  u16* gb  = (u16*)(ws+off); off += XB;  // silu(x Wg^T)
  float* E = (float*)(ws+off); off += EB;
  float* S = (float*)(ws+off); off += EB;

  conv_f2b_k<<<dim3(2048), 256, 0, stream>>>(x,  xb,  MTOT*D_M/4);
  conv_w4_k<<<dim3(1024,4), 256, 0, stream>>>(Wq, Wv, Wg, Wo, Wqb, Wvb, Wgb, Wob);

  // q / v / gate projections in one launch (z = 0,1,2), silu fused for gate
  gemm256<0><<<dim3(MTOT/256, D_M/256, 3), 512, 0, stream>>>(xb, Wqb, Wvb, Wgb, qb, vb, gb);

  scan1_k<<<dim3(NCH, BB), 256, 0, stream>>>(vb, E, decay);
  scan2_k<<<dim3(4), 256, 0, stream>>>(E, S, decay);

  fuse_ln_k<<<dim3(MTOT), 256, 0, stream>>>(qb, vb, gb, S, decay, gamma, beta, qb);

  // out = y_ln @ Wo^T (fp32 output)
  gemm256<1><<<dim3(MTOT/256, D_M/256, 1), 512, 0, stream>>>(qb, Wob, Wob, Wob,
                                                             (void*)out, (void*)out, (void*)out);
}